// Round 1
// baseline (313.059 us; speedup 1.0000x reference)
//
#include <hip/hip_runtime.h>

typedef __bf16 bf16_t;
typedef float  f32x4_t  __attribute__((ext_vector_type(4)));
typedef bf16_t bf16x8_t __attribute__((ext_vector_type(8)));

#define BATCH  4
#define S_LEN  4096
#define DMODEL 1024
#define HDIM   64

// ---------------------------------------------------------------------------
// Kernel 1: fused QKV projection (fp32 compute), emits bf16 Q (pre-scaled by
// 1/8), bf16 K (row-major [B*S][64]) and bf16 V transposed ([B][64][S]).
// Block = 256 threads = 4 waves; each wave computes 8 rows x 64 outputs x 3.
// Lane = output column h. W loads coalesced (64 lanes x 4B), x loads
// wave-uniform float4 (L1-served).
// ---------------------------------------------------------------------------
__global__ __launch_bounds__(256) void qkv_proj_kernel(
    const float* __restrict__ x,
    const float* __restrict__ Wk, const float* __restrict__ bk,
    const float* __restrict__ Wq, const float* __restrict__ bq,
    const float* __restrict__ Wv, const float* __restrict__ bv,
    bf16_t* __restrict__ Qb, bf16_t* __restrict__ Kb, bf16_t* __restrict__ Vt)
{
    __shared__ bf16_t vlds[64][32];

    const int tid  = threadIdx.x;
    const int lane = tid & 63;
    const int w    = tid >> 6;
    const long rowbase = (long)blockIdx.x * 32 + w * 8;
    const float* xr = x + rowbase * DMODEL;

    float accq[8], acck[8], accv[8];
#pragma unroll
    for (int r = 0; r < 8; ++r) { accq[r] = 0.f; acck[r] = 0.f; accv[r] = 0.f; }

    for (int d = 0; d < DMODEL; d += 4) {
        float wqv[4], wkv[4], wvv[4];
#pragma unroll
        for (int i = 0; i < 4; ++i) {
            wqv[i] = Wq[(d + i) * HDIM + lane];
            wkv[i] = Wk[(d + i) * HDIM + lane];
            wvv[i] = Wv[(d + i) * HDIM + lane];
        }
#pragma unroll
        for (int r = 0; r < 8; ++r) {
            const float4 xv = *reinterpret_cast<const float4*>(xr + (long)r * DMODEL + d);
            accq[r] = fmaf(xv.x, wqv[0], accq[r]);
            accq[r] = fmaf(xv.y, wqv[1], accq[r]);
            accq[r] = fmaf(xv.z, wqv[2], accq[r]);
            accq[r] = fmaf(xv.w, wqv[3], accq[r]);
            acck[r] = fmaf(xv.x, wkv[0], acck[r]);
            acck[r] = fmaf(xv.y, wkv[1], acck[r]);
            acck[r] = fmaf(xv.z, wkv[2], acck[r]);
            acck[r] = fmaf(xv.w, wkv[3], acck[r]);
            accv[r] = fmaf(xv.x, wvv[0], accv[r]);
            accv[r] = fmaf(xv.y, wvv[1], accv[r]);
            accv[r] = fmaf(xv.z, wvv[2], accv[r]);
            accv[r] = fmaf(xv.w, wvv[3], accv[r]);
        }
    }

    const float bqv = bq[lane], bkv = bk[lane], bvv = bv[lane];
#pragma unroll
    for (int r = 0; r < 8; ++r) {
        const long row = rowbase + r;
        Qb[row * HDIM + lane] = (bf16_t)((accq[r] + bqv) * 0.125f); // 1/sqrt(64)
        Kb[row * HDIM + lane] = (bf16_t)(acck[r] + bkv);
        vlds[lane][w * 8 + r] = (bf16_t)(accv[r] + bvv);
    }
    __syncthreads();

    // Write V transposed: Vt[b][h][s]; 64 h-rows x 32 s-cols per block.
    {
        const int bb = (int)(rowbase >> 12);             // batch (4096 rows/batch)
        const int s0 = (int)((blockIdx.x * 32) & 4095);  // block's first seq pos
        const int h  = tid >> 2;
        const int c  = (tid & 3) * 8;
        bf16x8_t vv = *reinterpret_cast<const bf16x8_t*>(&vlds[h][c]);
        *reinterpret_cast<bf16x8_t*>(&Vt[((long)(bb * 64 + h)) * S_LEN + s0 + c]) = vv;
    }
}

// ---------------------------------------------------------------------------
// Kernel 2: causal flash attention, bf16 MFMA (16x16x32), fp32 accum.
// One wave per 16-query tile; key blocks of 32 (two 16-key MFMA subtiles).
// Fragment layouts (HW-verified on gfx950):
//   A[m][k]: m = lane&15, k = (lane>>4)*8 + j (8 contiguous bf16)
//   B[k][n]: n = lane&15, k = (lane>>4)*8 + j
//   D[m][n]: n = lane&15, m = (lane>>4)*4 + reg
// ---------------------------------------------------------------------------
__global__ __launch_bounds__(64) void attn_kernel(
    const bf16_t* __restrict__ Qb, const bf16_t* __restrict__ Kb,
    const bf16_t* __restrict__ Vt, float* __restrict__ out)
{
    __shared__ bf16_t plds[16][40];   // P bounce buffer; stride 40 -> 80B rows

    const int lane = threadIdx.x;
    const int g    = lane >> 4;
    const int n    = lane & 15;
    const int b    = blockIdx.y;
    const int q0   = blockIdx.x * 16;
    const long bS  = (long)b * S_LEN;

    // Q A-fragments (two 32-wide h chunks), q pre-scaled by 1/8
    const bf16_t* qbase = &Qb[(bS + q0 + n) * HDIM + g * 8];
    const bf16x8_t aq0 = *reinterpret_cast<const bf16x8_t*>(qbase);
    const bf16x8_t aq1 = *reinterpret_cast<const bf16x8_t*>(qbase + 32);

    f32x4_t o0 = {0.f, 0.f, 0.f, 0.f}, o1 = o0, o2 = o0, o3 = o0;
    float mr[4], lr[4];
#pragma unroll
    for (int r = 0; r < 4; ++r) { mr[r] = -1e30f; lr[r] = 0.f; }

    const int kend = q0 + 16;   // keys 0..kend-1 needed (causal)
    for (int k0 = 0; k0 < kend; k0 += 32) {
        // ---- QK^T: B-frags straight from global K (contiguous 8 h per lane)
        const bf16_t* kbase = &Kb[(bS + k0 + n) * HDIM + g * 8];
        const bf16x8_t kb00 = *reinterpret_cast<const bf16x8_t*>(kbase);
        const bf16x8_t kb01 = *reinterpret_cast<const bf16x8_t*>(kbase + 32);
        const bf16x8_t kb10 = *reinterpret_cast<const bf16x8_t*>(kbase + 16 * HDIM);
        const bf16x8_t kb11 = *reinterpret_cast<const bf16x8_t*>(kbase + 16 * HDIM + 32);

        const f32x4_t zero = {0.f, 0.f, 0.f, 0.f};
        f32x4_t s0 = __builtin_amdgcn_mfma_f32_16x16x32_bf16(aq0, kb00, zero, 0, 0, 0);
        s0         = __builtin_amdgcn_mfma_f32_16x16x32_bf16(aq1, kb01, s0,   0, 0, 0);
        f32x4_t s1 = __builtin_amdgcn_mfma_f32_16x16x32_bf16(aq0, kb10, zero, 0, 0, 0);
        s1         = __builtin_amdgcn_mfma_f32_16x16x32_bf16(aq1, kb11, s1,   0, 0, 0);

        // ---- causal mask (q = q0+4g+r, key = k0+{0,16}+n)
#pragma unroll
        for (int r = 0; r < 4; ++r) {
            const int q = q0 + 4 * g + r;
            if (k0 + n > q)      s0[r] = -1e30f;
            if (k0 + 16 + n > q) s1[r] = -1e30f;
        }

        // ---- online softmax (row = 16 lanes sharing g; reduce over n)
        float pm[4];
#pragma unroll
        for (int r = 0; r < 4; ++r) {
            pm[r] = fmaxf(s0[r], s1[r]);
            pm[r] = fmaxf(pm[r], __shfl_xor(pm[r], 1));
            pm[r] = fmaxf(pm[r], __shfl_xor(pm[r], 2));
            pm[r] = fmaxf(pm[r], __shfl_xor(pm[r], 4));
            pm[r] = fmaxf(pm[r], __shfl_xor(pm[r], 8));
        }
        float alpha[4];
        f32x4_t p0, p1;
#pragma unroll
        for (int r = 0; r < 4; ++r) {
            const float mn = fmaxf(mr[r], pm[r]);
            alpha[r] = __expf(mr[r] - mn);
            mr[r]    = mn;
            p0[r] = __expf(s0[r] - mn);
            p1[r] = __expf(s1[r] - mn);
            float t = p0[r] + p1[r];
            t += __shfl_xor(t, 1);
            t += __shfl_xor(t, 2);
            t += __shfl_xor(t, 4);
            t += __shfl_xor(t, 8);
            lr[r] = lr[r] * alpha[r] + t;
        }

        // ---- P -> LDS (D-layout write), rescale O
#pragma unroll
        for (int r = 0; r < 4; ++r) {
            plds[4 * g + r][n]      = (bf16_t)p0[r];
            plds[4 * g + r][16 + n] = (bf16_t)p1[r];
        }
#pragma unroll
        for (int r = 0; r < 4; ++r) {
            o0[r] *= alpha[r]; o1[r] *= alpha[r];
            o2[r] *= alpha[r]; o3[r] *= alpha[r];
        }
        __syncthreads();   // single wave: orders LDS writes before A-frag read

        // ---- PV: A-frag of P from LDS (contiguous 8 keys), B-frags from Vt
        const bf16x8_t pa = *reinterpret_cast<const bf16x8_t*>(&plds[n][g * 8]);
        const bf16_t* vbase = &Vt[((long)(b * 64) + n) * S_LEN + k0 + g * 8];
        const bf16x8_t vb0 = *reinterpret_cast<const bf16x8_t*>(vbase);
        const bf16x8_t vb1 = *reinterpret_cast<const bf16x8_t*>(vbase + 16 * S_LEN);
        const bf16x8_t vb2 = *reinterpret_cast<const bf16x8_t*>(vbase + 32 * S_LEN);
        const bf16x8_t vb3 = *reinterpret_cast<const bf16x8_t*>(vbase + 48 * S_LEN);
        o0 = __builtin_amdgcn_mfma_f32_16x16x32_bf16(pa, vb0, o0, 0, 0, 0);
        o1 = __builtin_amdgcn_mfma_f32_16x16x32_bf16(pa, vb1, o1, 0, 0, 0);
        o2 = __builtin_amdgcn_mfma_f32_16x16x32_bf16(pa, vb2, o2, 0, 0, 0);
        o3 = __builtin_amdgcn_mfma_f32_16x16x32_bf16(pa, vb3, o3, 0, 0, 0);
    }

    // ---- epilogue: divide by l, write fp32 out
#pragma unroll
    for (int r = 0; r < 4; ++r) {
        const float inv = 1.f / lr[r];
        float* orow = out + (bS + q0 + 4 * g + r) * HDIM;
        orow[n]      = o0[r] * inv;
        orow[16 + n] = o1[r] * inv;
        orow[32 + n] = o2[r] * inv;
        orow[48 + n] = o3[r] * inv;
    }
}

// ---------------------------------------------------------------------------
extern "C" void kernel_launch(void* const* d_in, const int* in_sizes, int n_in,
                              void* d_out, int out_size, void* d_ws, size_t ws_size,
                              hipStream_t stream)
{
    const float* x  = (const float*)d_in[0];
    const float* Wk = (const float*)d_in[1];
    const float* bk = (const float*)d_in[2];
    const float* Wq = (const float*)d_in[3];
    const float* bq = (const float*)d_in[4];
    const float* Wv = (const float*)d_in[5];
    const float* bv = (const float*)d_in[6];
    float* out = (float*)d_out;

    const size_t elems = (size_t)BATCH * S_LEN * HDIM;  // 1,048,576
    bf16_t* Qb = (bf16_t*)d_ws;
    bf16_t* Kb = Qb + elems;
    bf16_t* Vt = Kb + elems;   // total 6 MB of ws

    qkv_proj_kernel<<<16384 / 32, 256, 0, stream>>>(x, Wk, bk, Wq, bq, Wv, bv,
                                                    Qb, Kb, Vt);
    attn_kernel<<<dim3(S_LEN / 16, BATCH), 64, 0, stream>>>(Qb, Kb, Vt, out);
}

// Round 2
// 144.689 us; speedup vs baseline: 2.1637x; 2.1637x over previous
//
#include <hip/hip_runtime.h>

typedef __bf16 bf16_t;
typedef float  f32x4_t  __attribute__((ext_vector_type(4)));
typedef bf16_t bf16x8_t __attribute__((ext_vector_type(8)));

#define BATCH  4
#define S_LEN  4096
#define DMODEL 1024
#define HDIM   64
#define NQT    (S_LEN / 16)   // 256 q-tiles per batch

// ---------------------------------------------------------------------------
// Kernel 0: transpose+cast W -> Wt[192][1024] bf16.  Rows 0-63 = Wq cols,
// 64-127 = Wk, 128-191 = Wv.  64x64 tiles through LDS, coalesced both sides.
// ---------------------------------------------------------------------------
__global__ __launch_bounds__(256) void wt_kernel(
    const float* __restrict__ Wk, const float* __restrict__ Wq,
    const float* __restrict__ Wv, bf16_t* __restrict__ Wt)
{
    __shared__ bf16_t t[64][65];
    const float* W = (blockIdx.y == 0) ? Wq : (blockIdx.y == 1) ? Wk : Wv;
    const int k0 = blockIdx.x * 64;
    const int a = threadIdx.x & 63, r = threadIdx.x >> 6;
#pragma unroll
    for (int i = 0; i < 16; ++i) {
        const int k = r + i * 4;
        t[k][a] = (bf16_t)W[(long)(k0 + k) * HDIM + a];  // coalesced over a
    }
    __syncthreads();
#pragma unroll
    for (int i = 0; i < 16; ++i) {
        const int h = r + i * 4;
        Wt[((long)(blockIdx.y * 64 + h)) * DMODEL + k0 + a] = t[a][h];
    }
}

// ---------------------------------------------------------------------------
// Kernel 1: QKV projection via bf16 MFMA (fp32 accum).
// Grid 256 blocks x 512 thr (8 waves).  Block: 64 rows x all 192 cols, BK=64.
// LDS tiles XOR-swizzled (T2): byte = row*128 + ((seg ^ (row&7))*16).
// Wave (w>>2) = m-half (32 rows), (w&3) = n-quad (48 cols = 3 tiles).
// Emits: Qb[row][h] bf16 pre-scaled 1/8, Kb[row][h], Vt[b*64+h][s] (LDS bounce).
// ---------------------------------------------------------------------------
__global__ __launch_bounds__(512) void qkv_mfma_kernel(
    const float* __restrict__ x, const bf16_t* __restrict__ Wt,
    const float* __restrict__ bk, const float* __restrict__ bq,
    const float* __restrict__ bv,
    bf16_t* __restrict__ Qb, bf16_t* __restrict__ Kb, bf16_t* __restrict__ Vt)
{
    __shared__ bf16_t xs[64 * 64];    // 8 KB, swizzled
    __shared__ bf16_t ws[192 * 64];   // 24 KB, swizzled
    __shared__ bf16_t vs[64][72];     // V transpose bounce, 9.2 KB

    const int tid  = threadIdx.x;
    const int lane = tid & 63;
    const int w    = tid >> 6;
    const int g    = lane >> 4, n = lane & 15;
    const long rowbase = (long)blockIdx.x * 64;

    const int srow = tid >> 3, sseg = tid & 7;   // x staging task
    const int mrow = (w >> 2) * 32;
    const int ncol = (w & 3) * 48;

    f32x4_t acc[2][3];
#pragma unroll
    for (int mt = 0; mt < 2; ++mt)
#pragma unroll
        for (int nt = 0; nt < 3; ++nt) acc[mt][nt] = (f32x4_t){0.f, 0.f, 0.f, 0.f};

    for (int kc = 0; kc < 16; ++kc) {
        const int k0 = kc * 64;
        // ---- issue global loads into regs first (overlap with drain)
        const float* xp = x + (rowbase + srow) * DMODEL + k0 + sseg * 8;
        const float4 xa = *reinterpret_cast<const float4*>(xp);
        const float4 xb = *reinterpret_cast<const float4*>(xp + 4);
        bf16x8_t wreg[3];
#pragma unroll
        for (int i = 0; i < 3; ++i) {
            const int s = tid + i * 512;
            wreg[i] = *reinterpret_cast<const bf16x8_t*>(
                Wt + ((long)(s >> 3)) * DMODEL + k0 + (s & 7) * 8);
        }
        bf16x8_t xv;
        xv[0] = (bf16_t)xa.x; xv[1] = (bf16_t)xa.y;
        xv[2] = (bf16_t)xa.z; xv[3] = (bf16_t)xa.w;
        xv[4] = (bf16_t)xb.x; xv[5] = (bf16_t)xb.y;
        xv[6] = (bf16_t)xb.z; xv[7] = (bf16_t)xb.w;

        __syncthreads();   // previous chunk's LDS reads done
        *reinterpret_cast<bf16x8_t*>(
            (char*)xs + srow * 128 + ((sseg ^ (srow & 7)) * 16)) = xv;
#pragma unroll
        for (int i = 0; i < 3; ++i) {
            const int s = tid + i * 512;
            const int wrow = s >> 3, wseg = s & 7;
            *reinterpret_cast<bf16x8_t*>(
                (char*)ws + wrow * 128 + ((wseg ^ (wrow & 7)) * 16)) = wreg[i];
        }
        __syncthreads();

        // ---- compute: 2 k-steps x (2 m-tiles x 3 n-tiles)
#pragma unroll
        for (int ks = 0; ks < 2; ++ks) {
            const int sb = ks * 4;   // k-seg base (32 bf16 = 4 segs)
            bf16x8_t afr[2], bfr[3];
#pragma unroll
            for (int mt = 0; mt < 2; ++mt) {
                const int row = mrow + mt * 16 + n;
                afr[mt] = *reinterpret_cast<const bf16x8_t*>(
                    (char*)xs + row * 128 + (((sb + g) ^ (row & 7)) * 16));
            }
#pragma unroll
            for (int nt = 0; nt < 3; ++nt) {
                const int row = ncol + nt * 16 + n;
                bfr[nt] = *reinterpret_cast<const bf16x8_t*>(
                    (char*)ws + row * 128 + (((sb + g) ^ (row & 7)) * 16));
            }
#pragma unroll
            for (int mt = 0; mt < 2; ++mt)
#pragma unroll
                for (int nt = 0; nt < 3; ++nt)
                    acc[mt][nt] = __builtin_amdgcn_mfma_f32_16x16x32_bf16(
                        afr[mt], bfr[nt], acc[mt][nt], 0, 0, 0);
        }
    }

    // ---- epilogue: bias (+1/8 scale for Q), write Q/K direct, V via bounce
#pragma unroll
    for (int nt = 0; nt < 3; ++nt) {
        const int c = ncol + nt * 16 + n;
        float bias;
        if (c < 64)       bias = bq[c];
        else if (c < 128) bias = bk[c - 64];
        else              bias = bv[c - 128];
#pragma unroll
        for (int mt = 0; mt < 2; ++mt) {
#pragma unroll
            for (int r = 0; r < 4; ++r) {
                const int row = mrow + mt * 16 + 4 * g + r;
                const float val = acc[mt][nt][r] + bias;
                if (c < 64)
                    Qb[(rowbase + row) * HDIM + c] = (bf16_t)(val * 0.125f);
                else if (c < 128)
                    Kb[(rowbase + row) * HDIM + (c - 64)] = (bf16_t)val;
                else
                    vs[c - 128][row] = (bf16_t)val;
            }
        }
    }
    __syncthreads();
    {
        const int h = tid >> 3, sj = (tid & 7) * 8;
        const int bb = (int)(rowbase >> 12);
        const int s0 = (int)(rowbase & (S_LEN - 1));
        const bf16x8_t vv = *reinterpret_cast<const bf16x8_t*>(&vs[h][sj]);
        *reinterpret_cast<bf16x8_t*>(
            Vt + ((long)(bb * 64 + h)) * S_LEN + s0 + sj) = vv;
    }
}

// ---------------------------------------------------------------------------
// Kernel 2: causal flash attention, split-K x4.
// Block = 4 waves on one 16-query tile; wave w takes key-blocks j = w mod 4,
// private online softmax; merge (m,l,O) through LDS.  Even/odd tile remap
// pairs long+short tiles for dispatch balance.
// ---------------------------------------------------------------------------
__global__ __launch_bounds__(256) void attn_kernel(
    const bf16_t* __restrict__ Qb, const bf16_t* __restrict__ Kb,
    const bf16_t* __restrict__ Vt, float* __restrict__ out)
{
    __shared__ bf16_t plds[4][2][16][40];   // per-wave, double-buffered P
    __shared__ float  olds[4][16][64];
    __shared__ float  mlds[4][16];
    __shared__ float  llds[4][16];

    const int tid  = threadIdx.x;
    const int w    = tid >> 6;
    const int lane = tid & 63;
    const int g    = lane >> 4, n = lane & 15;
    const int b    = blockIdx.y;
    const int bx   = blockIdx.x;
    const int tile = (bx & 1) ? (NQT - 1 - (bx >> 1)) : (bx >> 1);
    const int q0   = tile * 16;
    const long bS  = (long)b * S_LEN;

    const bf16_t* qbase = &Qb[(bS + q0 + n) * HDIM + g * 8];
    const bf16x8_t aq0 = *reinterpret_cast<const bf16x8_t*>(qbase);
    const bf16x8_t aq1 = *reinterpret_cast<const bf16x8_t*>(qbase + 32);

    f32x4_t o0 = {0.f, 0.f, 0.f, 0.f}, o1 = o0, o2 = o0, o3 = o0;
    float mr[4], lr[4];
#pragma unroll
    for (int r = 0; r < 4; ++r) { mr[r] = -1e30f; lr[r] = 0.f; }

    const int nkb = (q0 >> 5) + 1;   // # of 32-key blocks (causal)
    int buf = 0;
    for (int j = w; j < nkb; j += 4, buf ^= 1) {
        const int k0 = j * 32;
        // ---- QK^T
        const bf16_t* kbase = &Kb[(bS + k0 + n) * HDIM + g * 8];
        const bf16x8_t kb00 = *reinterpret_cast<const bf16x8_t*>(kbase);
        const bf16x8_t kb01 = *reinterpret_cast<const bf16x8_t*>(kbase + 32);
        const bf16x8_t kb10 = *reinterpret_cast<const bf16x8_t*>(kbase + 16 * HDIM);
        const bf16x8_t kb11 = *reinterpret_cast<const bf16x8_t*>(kbase + 16 * HDIM + 32);

        const f32x4_t zero = {0.f, 0.f, 0.f, 0.f};
        f32x4_t s0 = __builtin_amdgcn_mfma_f32_16x16x32_bf16(aq0, kb00, zero, 0, 0, 0);
        s0         = __builtin_amdgcn_mfma_f32_16x16x32_bf16(aq1, kb01, s0,   0, 0, 0);
        f32x4_t s1 = __builtin_amdgcn_mfma_f32_16x16x32_bf16(aq0, kb10, zero, 0, 0, 0);
        s1         = __builtin_amdgcn_mfma_f32_16x16x32_bf16(aq1, kb11, s1,   0, 0, 0);

        // ---- causal mask
#pragma unroll
        for (int r = 0; r < 4; ++r) {
            const int q = q0 + 4 * g + r;
            if (k0 + n > q)      s0[r] = -1e30f;
            if (k0 + 16 + n > q) s1[r] = -1e30f;
        }

        // ---- online softmax (reduce over the 16 lanes sharing g)
        float pm[4];
#pragma unroll
        for (int r = 0; r < 4; ++r) {
            pm[r] = fmaxf(s0[r], s1[r]);
            pm[r] = fmaxf(pm[r], __shfl_xor(pm[r], 1));
            pm[r] = fmaxf(pm[r], __shfl_xor(pm[r], 2));
            pm[r] = fmaxf(pm[r], __shfl_xor(pm[r], 4));
            pm[r] = fmaxf(pm[r], __shfl_xor(pm[r], 8));
        }
        float alpha[4];
        f32x4_t p0, p1;
#pragma unroll
        for (int r = 0; r < 4; ++r) {
            const float mn = fmaxf(mr[r], pm[r]);
            alpha[r] = __expf(mr[r] - mn);
            mr[r]    = mn;
            p0[r] = __expf(s0[r] - mn);
            p1[r] = __expf(s1[r] - mn);
            float t = p0[r] + p1[r];
            t += __shfl_xor(t, 1);
            t += __shfl_xor(t, 2);
            t += __shfl_xor(t, 4);
            t += __shfl_xor(t, 8);
            lr[r] = lr[r] * alpha[r] + t;
        }

        // ---- P -> LDS (D-layout), rescale O
#pragma unroll
        for (int r = 0; r < 4; ++r) {
            plds[w][buf][4 * g + r][n]      = (bf16_t)p0[r];
            plds[w][buf][4 * g + r][16 + n] = (bf16_t)p1[r];
        }
#pragma unroll
        for (int r = 0; r < 4; ++r) {
            o0[r] *= alpha[r]; o1[r] *= alpha[r];
            o2[r] *= alpha[r]; o3[r] *= alpha[r];
        }
        // same-wave LDS ordering: HW DS ops are in-order; fence the compiler
        asm volatile("s_waitcnt lgkmcnt(0)" ::: "memory");

        // ---- PV
        const bf16x8_t pa = *reinterpret_cast<const bf16x8_t*>(&plds[w][buf][n][g * 8]);
        asm volatile("" ::: "memory");   // keep pa read before next-iter writes
        const bf16_t* vbase = &Vt[((long)(b * 64) + n) * S_LEN + k0 + g * 8];
        const bf16x8_t vb0 = *reinterpret_cast<const bf16x8_t*>(vbase);
        const bf16x8_t vb1 = *reinterpret_cast<const bf16x8_t*>(vbase + 16 * S_LEN);
        const bf16x8_t vb2 = *reinterpret_cast<const bf16x8_t*>(vbase + 32 * S_LEN);
        const bf16x8_t vb3 = *reinterpret_cast<const bf16x8_t*>(vbase + 48 * S_LEN);
        o0 = __builtin_amdgcn_mfma_f32_16x16x32_bf16(pa, vb0, o0, 0, 0, 0);
        o1 = __builtin_amdgcn_mfma_f32_16x16x32_bf16(pa, vb1, o1, 0, 0, 0);
        o2 = __builtin_amdgcn_mfma_f32_16x16x32_bf16(pa, vb2, o2, 0, 0, 0);
        o3 = __builtin_amdgcn_mfma_f32_16x16x32_bf16(pa, vb3, o3, 0, 0, 0);
    }

    // ---- publish per-wave partial state
#pragma unroll
    for (int r = 0; r < 4; ++r) {
        const int row = 4 * g + r;
        if (n == 0) { mlds[w][row] = mr[r]; llds[w][row] = lr[r]; }
        olds[w][row][n]      = o0[r];
        olds[w][row][16 + n] = o1[r];
        olds[w][row][32 + n] = o2[r];
        olds[w][row][48 + n] = o3[r];
    }
    __syncthreads();

    // ---- merge 4 partials and write out (thread -> col c, 4 rows)
    {
        const int c  = tid & 63;
        const int rg = tid >> 6;
#pragma unroll
        for (int i = 0; i < 4; ++i) {
            const int row = rg * 4 + i;
            const float m0 = mlds[0][row], m1 = mlds[1][row];
            const float m2 = mlds[2][row], m3 = mlds[3][row];
            const float mm = fmaxf(fmaxf(m0, m1), fmaxf(m2, m3));
            const float a0 = __expf(m0 - mm), a1 = __expf(m1 - mm);
            const float a2 = __expf(m2 - mm), a3 = __expf(m3 - mm);
            const float den = llds[0][row] * a0 + llds[1][row] * a1 +
                              llds[2][row] * a2 + llds[3][row] * a3;
            const float num = olds[0][row][c] * a0 + olds[1][row][c] * a1 +
                              olds[2][row][c] * a2 + olds[3][row][c] * a3;
            out[(bS + q0 + row) * HDIM + c] = num / den;
        }
    }
}

// ---------------------------------------------------------------------------
extern "C" void kernel_launch(void* const* d_in, const int* in_sizes, int n_in,
                              void* d_out, int out_size, void* d_ws, size_t ws_size,
                              hipStream_t stream)
{
    const float* x  = (const float*)d_in[0];
    const float* Wk = (const float*)d_in[1];
    const float* bk = (const float*)d_in[2];
    const float* Wq = (const float*)d_in[3];
    const float* bq = (const float*)d_in[4];
    const float* Wv = (const float*)d_in[5];
    const float* bv = (const float*)d_in[6];
    float* out = (float*)d_out;

    const size_t elems = (size_t)BATCH * S_LEN * HDIM;  // 1,048,576
    bf16_t* Qb = (bf16_t*)d_ws;
    bf16_t* Kb = Qb + elems;
    bf16_t* Vt = Kb + elems;
    bf16_t* Wt = Vt + elems;   // 192*1024 bf16

    wt_kernel<<<dim3(DMODEL / 64, 3), 256, 0, stream>>>(Wk, Wq, Wv, Wt);
    qkv_mfma_kernel<<<256, 512, 0, stream>>>(x, Wt, bk, bq, bv, Qb, Kb, Vt);
    attn_kernel<<<dim3(NQT, BATCH), 256, 0, stream>>>(Qb, Kb, Vt, out);
}